// Round 1
// 232.785 us; speedup vs baseline: 1.0105x; 1.0105x over previous
//
#include <hip/hip_runtime.h>
#include <cstdint>
#include <cstddef>

#define DEVI __device__ __forceinline__

typedef short bf16x8 __attribute__((ext_vector_type(8)));
typedef short bf16x4 __attribute__((ext_vector_type(4)));
typedef float f32x4 __attribute__((ext_vector_type(4)));
typedef float f32x16 __attribute__((ext_vector_type(16)));
typedef unsigned short u16x4 __attribute__((ext_vector_type(4)));

constexpr int D_MODEL = 1024;
constexpr int HEADS = 16;
constexpr int DH = 64;
constexpr int SEQ = 2048;
constexpr int KDIM = 1024;

DEVI unsigned short f2bf(float f) {
  union { float f; unsigned u; } v; v.f = f;
  unsigned r = v.u + 0x7fffu + ((v.u >> 16) & 1u);
  return (unsigned short)(r >> 16);
}

// pack two fp32 -> two TRUNCATED bf16 in one dword (a = low16, b = high16)
DEVI unsigned pkbf(float a, float b) {
  return __builtin_amdgcn_perm(__float_as_uint(b), __float_as_uint(a), 0x07060302u);
}

DEVI void cp16(const void* g, void* l) {
  __builtin_amdgcn_global_load_lds(
      (const __attribute__((address_space(1))) void*)g,
      (__attribute__((address_space(3))) void*)l, 16, 0, 0);
}

#define BAR()        asm volatile("s_barrier" ::: "memory")
#define WAITVM(n)    asm volatile("s_waitcnt vmcnt(" #n ")" ::: "memory")

// ---------------- fused fp32 -> bf16 cast for all 7 tensors ----------------
__global__ void __launch_bounds__(256) castall(
    const float* __restrict__ q, const float* __restrict__ k, const float* __restrict__ v,
    const float* __restrict__ Wq, const float* __restrict__ Wk,
    const float* __restrict__ Wv, const float* __restrict__ Wo,
    unsigned short* __restrict__ qb, unsigned short* __restrict__ kb, unsigned short* __restrict__ vb,
    unsigned short* __restrict__ Wqb, unsigned short* __restrict__ Wkb,
    unsigned short* __restrict__ Wvb, unsigned short* __restrict__ Wob) {
  int bid = blockIdx.x;
  const float* s; unsigned short* d; int off;
  if (bid < 12288) {
    int w = bid >> 12; off = bid & 4095;
    s = (w == 0) ? q : ((w == 1) ? k : v);
    d = (w == 0) ? qb : ((w == 1) ? kb : vb);
  } else {
    int w = (bid - 12288) >> 10; off = bid & 1023;
    s = (w == 0) ? Wq : ((w == 1) ? Wk : ((w == 2) ? Wv : Wo));
    d = (w == 0) ? Wqb : ((w == 1) ? Wkb : ((w == 2) ? Wvb : Wob));
  }
  int i = (off * 256 + threadIdx.x) * 4;
  float4 x = *(const float4*)(s + i);
  u16x4 o; o[0] = f2bf(x.x); o[1] = f2bf(x.y); o[2] = f2bf(x.z); o[3] = f2bf(x.w);
  *(u16x4*)(d + i) = o;
}

// ---------------- QKV projection: 128x128 tile, triple-buffered, XCD-local ----------
__global__ void __launch_bounds__(256) qkv_gemm(
    const unsigned short* __restrict__ qb, const unsigned short* __restrict__ kb,
    const unsigned short* __restrict__ vb,
    const unsigned short* __restrict__ Wqb, const unsigned short* __restrict__ Wkb,
    const unsigned short* __restrict__ Wvb,
    const float* __restrict__ bq, const float* __restrict__ bk, const float* __restrict__ bv,
    unsigned short* __restrict__ Qh, unsigned short* __restrict__ Kh,
    unsigned short* __restrict__ Vt, float qscale) {
  __shared__ unsigned short As[3][128 * 32];
  __shared__ unsigned short Bs[3][128 * 32];
  const int bid = blockIdx.x, seg = bid >> 8, inner = bid & 255;
  const int bm = inner & 31, bn = inner >> 5;          // XCD-local swizzle
  const unsigned short* A = (seg == 0) ? qb : ((seg == 1) ? kb : vb);
  const unsigned short* W = (seg == 0) ? Wqb : ((seg == 1) ? Wkb : Wvb);
  const float* bias = (seg == 0) ? bq : ((seg == 1) ? bk : bv);
  unsigned short* O = (seg == 0) ? Qh : ((seg == 1) ? Kh : Vt);
  const float oscale = (seg == 0) ? qscale : 1.0f;
  const int mode = (seg == 2) ? 1 : 0;

  const int tid = threadIdx.x, lane = tid & 63, wave = tid >> 6;
  const int l16 = lane & 15, quad = lane >> 4;
  const int wm = (wave >> 1) * 64, wn = (wave & 1) * 64;
  const int sw = (l16 >> 1) & 3;
  f32x4 acc[4][4] = {};

  const int r0 = tid >> 2, p0 = tid & 3;
  const int c0 = (p0 ^ ((r0 >> 1) & 3)) * 8;
  const int r1 = (256 + tid) >> 2;
  const int c1 = (p0 ^ ((r1 >> 1) & 3)) * 8;
  const unsigned short* Arow0 = A + (size_t)(bm * 128 + r0) * KDIM + c0;
  const unsigned short* Arow1 = A + (size_t)(bm * 128 + r1) * KDIM + c1;
  const unsigned short* Wrow0 = W + (size_t)(bn * 128 + r0) * KDIM + c0;
  const unsigned short* Wrow1 = W + (size_t)(bn * 128 + r1) * KDIM + c1;

#define QKV_ISSUE(K0, P)                                    \
  do {                                                      \
    cp16(Arow0 + (K0), &As[P][tid * 8]);                    \
    cp16(Arow1 + (K0), &As[P][(256 + tid) * 8]);            \
    cp16(Wrow0 + (K0), &Bs[P][tid * 8]);                    \
    cp16(Wrow1 + (K0), &Bs[P][(256 + tid) * 8]);            \
  } while (0)

#define QKV_COMPUTE(P)                                                             \
  do {                                                                             \
    bf16x8 af[4], bfr[4];                                                          \
    _Pragma("unroll") for (int t = 0; t < 4; ++t)                                  \
        af[t] = *(const bf16x8*)&As[P][(wm + t * 16 + l16) * 32 + ((quad ^ sw) * 8)]; \
    _Pragma("unroll") for (int t = 0; t < 4; ++t)                                  \
        bfr[t] = *(const bf16x8*)&Bs[P][(wn + t * 16 + l16) * 32 + ((quad ^ sw) * 8)]; \
    _Pragma("unroll") for (int i = 0; i < 4; ++i)                                  \
        _Pragma("unroll") for (int j = 0; j < 4; ++j)                              \
            acc[i][j] = __builtin_amdgcn_mfma_f32_16x16x32_bf16(af[i], bfr[j],     \
                                                                acc[i][j], 0, 0, 0); \
  } while (0)

  QKV_ISSUE(0, 0);
  QKV_ISSUE(32, 1);
  for (int k = 0; k < 30; k += 3) {
    BAR(); QKV_ISSUE((k + 2) * 32, 2); WAITVM(8); BAR(); QKV_COMPUTE(0);
    BAR(); QKV_ISSUE((k + 3) * 32, 0); WAITVM(8); BAR(); QKV_COMPUTE(1);
    BAR(); QKV_ISSUE((k + 4) * 32, 1); WAITVM(8); BAR(); QKV_COMPUTE(2);
  }
  WAITVM(4); BAR(); QKV_COMPUTE(0);   // stage 30
  WAITVM(0); BAR(); QKV_COMPUTE(1);   // stage 31

#pragma unroll
  for (int i = 0; i < 4; ++i) {
#pragma unroll
    for (int j = 0; j < 4; ++j) {
      const int col = bn * 128 + wn + j * 16 + l16;
      const float bv = bias[col];
#pragma unroll
      for (int r = 0; r < 4; ++r) {
        const int row = bm * 128 + wm + i * 16 + quad * 4 + r;
        const float val = (acc[i][j][r] + bv) * oscale;
        const int b = row >> 11, s = row & (SEQ - 1);
        const int h = col >> 6, d = col & (DH - 1);
        size_t idx;
        if (mode == 0) idx = ((size_t)(b * HEADS + h) * SEQ + s) * DH + d;
        else           idx = ((size_t)(b * HEADS + h) * DH + d) * SEQ + s;
        O[idx] = f2bf(val);
      }
    }
  }
#undef QKV_ISSUE
#undef QKV_COMPUTE
}

// ---------------- output projection: 64x128 tile, triple-buffered, XCD-local ------
__global__ void __launch_bounds__(256) out_gemm(const unsigned short* __restrict__ AO,
                                                const unsigned short* __restrict__ Wob,
                                                const float* __restrict__ bo,
                                                float* __restrict__ out) {
  __shared__ unsigned short As[3][64 * 32];
  __shared__ unsigned short Bs[3][128 * 32];
  const int bid = blockIdx.x, bm = bid & 63, bn = bid >> 6;
  const int tid = threadIdx.x, lane = tid & 63, wave = tid >> 6;
  const int l16 = lane & 15, quad = lane >> 4;
  const int wn = wave * 32;
  const int sw = (l16 >> 1) & 3;
  f32x4 acc[4][2] = {};

  const int ra = tid >> 2, pa = tid & 3;
  const int ca = (pa ^ ((ra >> 1) & 3)) * 8;
  const int r1 = (256 + tid) >> 2;
  const int c1 = (pa ^ ((r1 >> 1) & 3)) * 8;
  const unsigned short* Arow  = AO + (size_t)(bm * 64 + ra) * KDIM + ca;
  const unsigned short* Wrow0 = Wob + (size_t)(bn * 128 + ra) * KDIM + ca;
  const unsigned short* Wrow1 = Wob + (size_t)(bn * 128 + r1) * KDIM + c1;

#define OUT_ISSUE(K0, P)                                    \
  do {                                                      \
    cp16(Arow + (K0), &As[P][tid * 8]);                     \
    cp16(Wrow0 + (K0), &Bs[P][tid * 8]);                    \
    cp16(Wrow1 + (K0), &Bs[P][(256 + tid) * 8]);            \
  } while (0)

#define OUT_COMPUTE(P)                                                             \
  do {                                                                             \
    bf16x8 af[4], bfr[2];                                                          \
    _Pragma("unroll") for (int t = 0; t < 4; ++t)                                  \
        af[t] = *(const bf16x8*)&As[P][(t * 16 + l16) * 32 + ((quad ^ sw) * 8)];   \
    _Pragma("unroll") for (int u = 0; u < 2; ++u)                                  \
        bfr[u] = *(const bf16x8*)&Bs[P][(wn + u * 16 + l16) * 32 + ((quad ^ sw) * 8)]; \
    _Pragma("unroll") for (int i = 0; i < 4; ++i)                                  \
        _Pragma("unroll") for (int j = 0; j < 2; ++j)                              \
            acc[i][j] = __builtin_amdgcn_mfma_f32_16x16x32_bf16(af[i], bfr[j],     \
                                                                acc[i][j], 0, 0, 0); \
  } while (0)

  OUT_ISSUE(0, 0);
  OUT_ISSUE(32, 1);
  for (int k = 0; k < 30; k += 3) {
    BAR(); OUT_ISSUE((k + 2) * 32, 2); WAITVM(6); BAR(); OUT_COMPUTE(0);
    BAR(); OUT_ISSUE((k + 3) * 32, 0); WAITVM(6); BAR(); OUT_COMPUTE(1);
    BAR(); OUT_ISSUE((k + 4) * 32, 1); WAITVM(6); BAR(); OUT_COMPUTE(2);
  }
  WAITVM(3); BAR(); OUT_COMPUTE(0);   // stage 30
  WAITVM(0); BAR(); OUT_COMPUTE(1);   // stage 31

#pragma unroll
  for (int i = 0; i < 4; ++i)
#pragma unroll
    for (int j = 0; j < 2; ++j) {
      const int col = bn * 128 + wn + j * 16 + l16;
      const float bv = bo[col];
#pragma unroll
      for (int r = 0; r < 4; ++r) {
        const int row = bm * 64 + i * 16 + quad * 4 + r;
        out[(size_t)row * D_MODEL + col] = acc[i][j][r] + bv;
      }
    }
#undef OUT_ISSUE
#undef OUT_COMPUTE
}

// ---------------- flash attention ------------------------------------------------
// Changes vs previous version:
//  * PV now uses v_mfma_f32_32x32x16_bf16 (full rate) instead of 32x32x8 (half
//    rate).  The per-lane P row (16 f32 covering keys (r&3)+8*(r>>2)+4*hh) is
//    packed to bf16 and redistributed with v_permlane32_swap_b32 so each lane
//    holds the B-operand fragment k = 8*hh + e for a 16-key contraction block:
//      X',Y' = swap(pack(p[8c..8c+3]), pack(p[8c+4..8c+7]))
//      fragment dwords = (X'0, X'1, Y'0, Y'1)
//    V is then read as ds_read_b128 (8-lane phases hit 8 distinct XOR slots ->
//    conflict-free), replacing the 2-way-conflicting b64 reads.
//  * K/V staging double-buffered (2 x 32 KB) with counted vmcnt(8) + raw
//    s_barrier: the per-kc vmcnt(0) drain (L2 latency x16) is now hidden.
//  * s_setprio(1) around the compute phase (T5).
__global__ void __launch_bounds__(256) attn(const unsigned short* __restrict__ Qh,
                                            const unsigned short* __restrict__ Kh,
                                            const unsigned short* __restrict__ Vt,
                                            unsigned short* __restrict__ AO) {
  __shared__ __align__(16) char smem[65536];
  // stage p: Ks = smem + p*32768          [128 key][64 dh], XOR-swizzled
  //          Vs = smem + p*32768 + 16384  [64 d][128 key],  XOR-swizzled

  const int bid = blockIdx.x;
  const int qt = bid >> 5, head = bid & 31, b = head >> 4, h = head & 15;
  const int tid = threadIdx.x;
  const int lane = tid & 63, wave = tid >> 6;
  const int wq = wave >> 1, wk = wave & 1;
  const int l31 = lane & 31, hh = lane >> 5;

  const unsigned short* Qhead = Qh + (size_t)(b * HEADS + h) * SEQ * DH;
  const unsigned short* Khead = Kh + (size_t)(b * HEADS + h) * SEQ * DH;
  const unsigned short* Vhead = Vt + (size_t)(b * HEADS + h) * DH * SEQ;

  const int qrow = qt * 64 + wq * 32 + l31;
  bf16x8 aq[4];
#pragma unroll
  for (int it = 0; it < 4; ++it)
    aq[it] = *(const bf16x8*)&Qhead[(size_t)qrow * DH + it * 16 + hh * 8];

  f32x16 oacc[2] = {};
  float lsum = 0.f;

  const int krow = tid >> 3, kpb = tid & 7;   // K staging: 4 chunks of 32 rows
  const int vd = tid >> 4, vpb = tid & 15;    // V staging: 4 chunks of 16 d

#define ATT_STAGE(KC, P)                                                      \
  do {                                                                        \
    unsigned short* Ksp = (unsigned short*)(smem + (P) * 32768);              \
    unsigned short* Vsp = (unsigned short*)(smem + (P) * 32768 + 16384);      \
    _Pragma("unroll") for (int c = 0; c < 4; ++c) {                           \
      int row = c * 32 + krow;                                                \
      int jb = kpb ^ (row & 7);                                               \
      cp16(Khead + (size_t)((KC) * 128 + row) * DH + jb * 8,                  \
           &Ksp[(c * 256 + tid) * 8]);                                        \
    }                                                                         \
    _Pragma("unroll") for (int c = 0; c < 4; ++c) {                           \
      int d = c * 16 + vd;                                                    \
      int jb = vpb ^ (d & 7);                                                 \
      cp16(Vhead + (size_t)d * SEQ + (KC) * 128 + jb * 8,                     \
           &Vsp[(c * 256 + tid) * 8]);                                        \
    }                                                                         \
  } while (0)

#define ATT_COMPUTE(P)                                                        \
  do {                                                                        \
    const unsigned short* Ksp = (const unsigned short*)(smem + (P) * 32768);  \
    const unsigned short* Vsp =                                               \
        (const unsigned short*)(smem + (P) * 32768 + 16384);                  \
    __builtin_amdgcn_s_setprio(1);                                            \
    _Pragma("unroll") for (int sub = 0; sub < 2; ++sub) {                     \
      const int kb32 = sub * 64 + wk * 32;                                    \
      const int key = kb32 + l31;                                             \
      f32x16 sa = {};                                                         \
      _Pragma("unroll") for (int it = 0; it < 4; ++it) {                      \
        const int sblk = (2 * it + hh) ^ (key & 7);                           \
        bf16x8 ak = *(const bf16x8*)&Ksp[key * 64 + sblk * 8];                \
        sa = __builtin_amdgcn_mfma_f32_32x32x16_bf16(ak, aq[it], sa, 0, 0, 0);\
      }                                                                       \
      float p[16];                                                            \
      _Pragma("unroll") for (int r = 0; r < 16; ++r) {                        \
        p[r] = __builtin_amdgcn_exp2f(sa[r]);                                 \
        lsum += p[r];                                                         \
      }                                                                       \
      _Pragma("unroll") for (int c = 0; c < 2; ++c) {                         \
        unsigned x0 = pkbf(p[8 * c + 0], p[8 * c + 1]);                       \
        unsigned x1 = pkbf(p[8 * c + 2], p[8 * c + 3]);                       \
        unsigned y0 = pkbf(p[8 * c + 4], p[8 * c + 5]);                       \
        unsigned y1 = pkbf(p[8 * c + 6], p[8 * c + 7]);                       \
        asm("v_permlane32_swap_b32 %0, %1" : "+v"(x0), "+v"(y0));             \
        asm("v_permlane32_swap_b32 %0, %1" : "+v"(x1), "+v"(y1));             \
        union { unsigned u[4]; bf16x8 s; } pb;                                \
        pb.u[0] = x0; pb.u[1] = x1; pb.u[2] = y0; pb.u[3] = y1;               \
        const int K8 = sub * 8 + wk * 4 + 2 * c + hh;                         \
        _Pragma("unroll") for (int dh2 = 0; dh2 < 2; ++dh2) {                 \
          const int d = dh2 * 32 + l31;                                       \
          const int sv = K8 ^ (d & 7);                                        \
          bf16x8 av = *(const bf16x8*)&Vsp[d * 128 + sv * 8];                 \
          oacc[dh2] = __builtin_amdgcn_mfma_f32_32x32x16_bf16(av, pb.s,       \
                                                              oacc[dh2],     \
                                                              0, 0, 0);      \
        }                                                                     \
      }                                                                       \
    }                                                                         \
    __builtin_amdgcn_s_setprio(0);                                            \
  } while (0)

  ATT_STAGE(0, 0);
  for (int kc = 0; kc < 15; ++kc) {
    BAR();                              // all waves done reading buf[(kc+1)&1]
    ATT_STAGE(kc + 1, (kc + 1) & 1);    // prefetch next tile
    WAITVM(8);                          // wait for tile kc's 8 loads only
    BAR();
    ATT_COMPUTE(kc & 1);
  }
  WAITVM(0);
  BAR();
  ATT_COMPUTE(1);                       // stage 15

  lsum += __shfl_xor(lsum, 32);

  // epilogue scratch overlays buffer 0 (last read at kc=14; all waves passed
  // the post-loop BAR before any write below; final compute reads buffer 1)
  float* epiF = (float*)smem;                            // [2 wq][2048]
  float* lbuf = (float*)(smem + 16384);                  // [4][32]
  unsigned short* Oq = (unsigned short*)(smem + 17408);  // [2 wq][32 q][68]

  if (l31 == lane) lbuf[wave * 32 + l31] = lsum;
  if (wk == 1) {
#pragma unroll
    for (int dh2 = 0; dh2 < 2; ++dh2)
#pragma unroll
      for (int r = 0; r < 16; ++r) {
        const int d = dh2 * 32 + (r & 3) + 8 * (r >> 2) + 4 * hh;
        epiF[wq * 2048 + d * 32 + l31] = oacc[dh2][r];
      }
  }
  __syncthreads();

  if (wk == 0) {
    const float linv = 1.0f / (lsum + lbuf[(wq * 2 + 1) * 32 + l31]);
#pragma unroll
    for (int dh2 = 0; dh2 < 2; ++dh2) {
#pragma unroll
      for (int r = 0; r < 16; r += 2) {
        const int d = dh2 * 32 + (r & 3) + 8 * (r >> 2) + 4 * hh;
        const float v0 = (oacc[dh2][r]     + epiF[wq * 2048 + d * 32 + l31]) * linv;
        const float v1 = (oacc[dh2][r + 1] + epiF[wq * 2048 + (d + 1) * 32 + l31]) * linv;
        *(unsigned*)&Oq[wq * 2176 + l31 * 68 + d] = pkbf(v0, v1);
      }
    }
  }
  __syncthreads();

  {
    const int qloc = tid >> 2, d0 = (tid & 3) * 16;
    const int base = (qloc >> 5) * 2176 + (qloc & 31) * 68 + d0;
    unsigned u[8];
#pragma unroll
    for (int i = 0; i < 8; ++i) u[i] = *(const unsigned*)&Oq[base + i * 2];
    unsigned short* dst = AO + ((size_t)(b * SEQ + qt * 64 + qloc)) * D_MODEL + h * 64 + d0;
    *(uint4*)dst       = make_uint4(u[0], u[1], u[2], u[3]);
    *(uint4*)(dst + 8) = make_uint4(u[4], u[5], u[6], u[7]);
  }
#undef ATT_STAGE
#undef ATT_COMPUTE
}

extern "C" void kernel_launch(void* const* d_in, const int* in_sizes, int n_in,
                              void* d_out, int out_size, void* d_ws, size_t ws_size,
                              hipStream_t stream) {
  const float* q  = (const float*)d_in[0];
  const float* k  = (const float*)d_in[1];
  const float* v  = (const float*)d_in[2];
  const float* Wq = (const float*)d_in[3];
  const float* bq = (const float*)d_in[4];
  const float* Wk = (const float*)d_in[5];
  const float* bk = (const float*)d_in[6];
  const float* Wv = (const float*)d_in[7];
  const float* bv = (const float*)d_in[8];
  const float* Wo = (const float*)d_in[9];
  const float* bo = (const float*)d_in[10];
  float* out = (float*)d_out;

  char* ws = (char*)d_ws;
  const size_t MB = 1ull << 20;
  unsigned short* qb  = (unsigned short*)(ws + 0 * MB);
  unsigned short* kb  = (unsigned short*)(ws + 8 * MB);
  unsigned short* vb  = (unsigned short*)(ws + 16 * MB);
  unsigned short* Wqb = (unsigned short*)(ws + 24 * MB);
  unsigned short* Wkb = (unsigned short*)(ws + 26 * MB);
  unsigned short* Wvb = (unsigned short*)(ws + 28 * MB);
  unsigned short* Wob = (unsigned short*)(ws + 30 * MB);
  unsigned short* Qh  = (unsigned short*)(ws + 32 * MB);
  unsigned short* Kh  = (unsigned short*)(ws + 40 * MB);
  unsigned short* Vt  = (unsigned short*)(ws + 48 * MB);
  unsigned short* AO  = (unsigned short*)(ws + 56 * MB);

  castall<<<16384, 256, 0, stream>>>(q, k, v, Wq, Wk, Wv, Wo,
                                     qb, kb, vb, Wqb, Wkb, Wvb, Wob);

  const float qscale = 0.125f * 1.44269504088896f;  // fold 1/sqrt(Dh) and log2(e) into Q
  qkv_gemm<<<768, 256, 0, stream>>>(qb, kb, vb, Wqb, Wkb, Wvb, bq, bk, bv,
                                    Qh, Kh, Vt, qscale);

  attn<<<1024, 256, 0, stream>>>(Qh, Kh, Vt, AO);

  out_gemm<<<512, 256, 0, stream>>>(AO, Wob, bo, out);
}

// Round 2
// 232.120 us; speedup vs baseline: 1.0134x; 1.0029x over previous
//
#include <hip/hip_runtime.h>
#include <cstdint>
#include <cstddef>

#define DEVI __device__ __forceinline__

typedef short bf16x8 __attribute__((ext_vector_type(8)));
typedef short bf16x4 __attribute__((ext_vector_type(4)));
typedef float f32x4 __attribute__((ext_vector_type(4)));
typedef float f32x16 __attribute__((ext_vector_type(16)));
typedef unsigned short u16x4 __attribute__((ext_vector_type(4)));

constexpr int D_MODEL = 1024;
constexpr int HEADS = 16;
constexpr int DH = 64;
constexpr int SEQ = 2048;
constexpr int KDIM = 1024;

DEVI unsigned short f2bf(float f) {
  union { float f; unsigned u; } v; v.f = f;
  unsigned r = v.u + 0x7fffu + ((v.u >> 16) & 1u);
  return (unsigned short)(r >> 16);
}

// pack two fp32 -> two TRUNCATED bf16 in one dword (a = low16, b = high16)
DEVI unsigned pkbf(float a, float b) {
  return __builtin_amdgcn_perm(__float_as_uint(b), __float_as_uint(a), 0x07060302u);
}

DEVI void cp16(const void* g, void* l) {
  __builtin_amdgcn_global_load_lds(
      (const __attribute__((address_space(1))) void*)g,
      (__attribute__((address_space(3))) void*)l, 16, 0, 0);
}

#define BAR()        asm volatile("s_barrier" ::: "memory")
#define WAITVM(n)    asm volatile("s_waitcnt vmcnt(" #n ")" ::: "memory")

// ---------------- fused fp32 -> bf16 cast for all 7 tensors ----------------
__global__ void __launch_bounds__(256) castall(
    const float* __restrict__ q, const float* __restrict__ k, const float* __restrict__ v,
    const float* __restrict__ Wq, const float* __restrict__ Wk,
    const float* __restrict__ Wv, const float* __restrict__ Wo,
    unsigned short* __restrict__ qb, unsigned short* __restrict__ kb, unsigned short* __restrict__ vb,
    unsigned short* __restrict__ Wqb, unsigned short* __restrict__ Wkb,
    unsigned short* __restrict__ Wvb, unsigned short* __restrict__ Wob) {
  int bid = blockIdx.x;
  const float* s; unsigned short* d; int off;
  if (bid < 12288) {
    int w = bid >> 12; off = bid & 4095;
    s = (w == 0) ? q : ((w == 1) ? k : v);
    d = (w == 0) ? qb : ((w == 1) ? kb : vb);
  } else {
    int w = (bid - 12288) >> 10; off = bid & 1023;
    s = (w == 0) ? Wq : ((w == 1) ? Wk : ((w == 2) ? Wv : Wo));
    d = (w == 0) ? Wqb : ((w == 1) ? Wkb : ((w == 2) ? Wvb : Wob));
  }
  int i = (off * 256 + threadIdx.x) * 4;
  float4 x = *(const float4*)(s + i);
  u16x4 o; o[0] = f2bf(x.x); o[1] = f2bf(x.y); o[2] = f2bf(x.z); o[3] = f2bf(x.w);
  *(u16x4*)(d + i) = o;
}

// ---------------- QKV projection: 128x128 tile, triple-buffered, XCD-local ----------
__global__ void __launch_bounds__(256) qkv_gemm(
    const unsigned short* __restrict__ qb, const unsigned short* __restrict__ kb,
    const unsigned short* __restrict__ vb,
    const unsigned short* __restrict__ Wqb, const unsigned short* __restrict__ Wkb,
    const unsigned short* __restrict__ Wvb,
    const float* __restrict__ bq, const float* __restrict__ bk, const float* __restrict__ bv,
    unsigned short* __restrict__ Qh, unsigned short* __restrict__ Kh,
    unsigned short* __restrict__ Vt, float qscale) {
  __shared__ unsigned short As[3][128 * 32];
  __shared__ unsigned short Bs[3][128 * 32];
  const int bid = blockIdx.x, seg = bid >> 8, inner = bid & 255;
  const int bm = inner & 31, bn = inner >> 5;          // XCD-local swizzle
  const unsigned short* A = (seg == 0) ? qb : ((seg == 1) ? kb : vb);
  const unsigned short* W = (seg == 0) ? Wqb : ((seg == 1) ? Wkb : Wvb);
  const float* bias = (seg == 0) ? bq : ((seg == 1) ? bk : bv);
  unsigned short* O = (seg == 0) ? Qh : ((seg == 1) ? Kh : Vt);
  const float oscale = (seg == 0) ? qscale : 1.0f;
  const int mode = (seg == 2) ? 1 : 0;

  const int tid = threadIdx.x, lane = tid & 63, wave = tid >> 6;
  const int l16 = lane & 15, quad = lane >> 4;
  const int wm = (wave >> 1) * 64, wn = (wave & 1) * 64;
  const int sw = (l16 >> 1) & 3;
  f32x4 acc[4][4] = {};

  const int r0 = tid >> 2, p0 = tid & 3;
  const int c0 = (p0 ^ ((r0 >> 1) & 3)) * 8;
  const int r1 = (256 + tid) >> 2;
  const int c1 = (p0 ^ ((r1 >> 1) & 3)) * 8;
  const unsigned short* Arow0 = A + (size_t)(bm * 128 + r0) * KDIM + c0;
  const unsigned short* Arow1 = A + (size_t)(bm * 128 + r1) * KDIM + c1;
  const unsigned short* Wrow0 = W + (size_t)(bn * 128 + r0) * KDIM + c0;
  const unsigned short* Wrow1 = W + (size_t)(bn * 128 + r1) * KDIM + c1;

#define QKV_ISSUE(K0, P)                                    \
  do {                                                      \
    cp16(Arow0 + (K0), &As[P][tid * 8]);                    \
    cp16(Arow1 + (K0), &As[P][(256 + tid) * 8]);            \
    cp16(Wrow0 + (K0), &Bs[P][tid * 8]);                    \
    cp16(Wrow1 + (K0), &Bs[P][(256 + tid) * 8]);            \
  } while (0)

#define QKV_COMPUTE(P)                                                             \
  do {                                                                             \
    bf16x8 af[4], bfr[4];                                                          \
    _Pragma("unroll") for (int t = 0; t < 4; ++t)                                  \
        af[t] = *(const bf16x8*)&As[P][(wm + t * 16 + l16) * 32 + ((quad ^ sw) * 8)]; \
    _Pragma("unroll") for (int t = 0; t < 4; ++t)                                  \
        bfr[t] = *(const bf16x8*)&Bs[P][(wn + t * 16 + l16) * 32 + ((quad ^ sw) * 8)]; \
    _Pragma("unroll") for (int i = 0; i < 4; ++i)                                  \
        _Pragma("unroll") for (int j = 0; j < 4; ++j)                              \
            acc[i][j] = __builtin_amdgcn_mfma_f32_16x16x32_bf16(af[i], bfr[j],     \
                                                                acc[i][j], 0, 0, 0); \
  } while (0)

  QKV_ISSUE(0, 0);
  QKV_ISSUE(32, 1);
  for (int k = 0; k < 30; k += 3) {
    BAR(); QKV_ISSUE((k + 2) * 32, 2); WAITVM(8); BAR(); QKV_COMPUTE(0);
    BAR(); QKV_ISSUE((k + 3) * 32, 0); WAITVM(8); BAR(); QKV_COMPUTE(1);
    BAR(); QKV_ISSUE((k + 4) * 32, 1); WAITVM(8); BAR(); QKV_COMPUTE(2);
  }
  WAITVM(4); BAR(); QKV_COMPUTE(0);   // stage 30
  WAITVM(0); BAR(); QKV_COMPUTE(1);   // stage 31

#pragma unroll
  for (int i = 0; i < 4; ++i) {
#pragma unroll
    for (int j = 0; j < 4; ++j) {
      const int col = bn * 128 + wn + j * 16 + l16;
      const float bv = bias[col];
#pragma unroll
      for (int r = 0; r < 4; ++r) {
        const int row = bm * 128 + wm + i * 16 + quad * 4 + r;
        const float val = (acc[i][j][r] + bv) * oscale;
        const int b = row >> 11, s = row & (SEQ - 1);
        const int h = col >> 6, d = col & (DH - 1);
        size_t idx;
        if (mode == 0) idx = ((size_t)(b * HEADS + h) * SEQ + s) * DH + d;
        else           idx = ((size_t)(b * HEADS + h) * DH + d) * SEQ + s;
        O[idx] = f2bf(val);
      }
    }
  }
#undef QKV_ISSUE
#undef QKV_COMPUTE
}

// ---------------- output projection: 64x128 tile, triple-buffered, XCD-local ------
__global__ void __launch_bounds__(256) out_gemm(const unsigned short* __restrict__ AO,
                                                const unsigned short* __restrict__ Wob,
                                                const float* __restrict__ bo,
                                                float* __restrict__ out) {
  __shared__ unsigned short As[3][64 * 32];
  __shared__ unsigned short Bs[3][128 * 32];
  const int bid = blockIdx.x, bm = bid & 63, bn = bid >> 6;
  const int tid = threadIdx.x, lane = tid & 63, wave = tid >> 6;
  const int l16 = lane & 15, quad = lane >> 4;
  const int wn = wave * 32;
  const int sw = (l16 >> 1) & 3;
  f32x4 acc[4][2] = {};

  const int ra = tid >> 2, pa = tid & 3;
  const int ca = (pa ^ ((ra >> 1) & 3)) * 8;
  const int r1 = (256 + tid) >> 2;
  const int c1 = (pa ^ ((r1 >> 1) & 3)) * 8;
  const unsigned short* Arow  = AO + (size_t)(bm * 64 + ra) * KDIM + ca;
  const unsigned short* Wrow0 = Wob + (size_t)(bn * 128 + ra) * KDIM + ca;
  const unsigned short* Wrow1 = Wob + (size_t)(bn * 128 + r1) * KDIM + c1;

#define OUT_ISSUE(K0, P)                                    \
  do {                                                      \
    cp16(Arow + (K0), &As[P][tid * 8]);                     \
    cp16(Wrow0 + (K0), &Bs[P][tid * 8]);                    \
    cp16(Wrow1 + (K0), &Bs[P][(256 + tid) * 8]);            \
  } while (0)

#define OUT_COMPUTE(P)                                                             \
  do {                                                                             \
    bf16x8 af[4], bfr[2];                                                          \
    _Pragma("unroll") for (int t = 0; t < 4; ++t)                                  \
        af[t] = *(const bf16x8*)&As[P][(t * 16 + l16) * 32 + ((quad ^ sw) * 8)];   \
    _Pragma("unroll") for (int u = 0; u < 2; ++u)                                  \
        bfr[u] = *(const bf16x8*)&Bs[P][(wn + u * 16 + l16) * 32 + ((quad ^ sw) * 8)]; \
    _Pragma("unroll") for (int i = 0; i < 4; ++i)                                  \
        _Pragma("unroll") for (int j = 0; j < 2; ++j)                              \
            acc[i][j] = __builtin_amdgcn_mfma_f32_16x16x32_bf16(af[i], bfr[j],     \
                                                                acc[i][j], 0, 0, 0); \
  } while (0)

  OUT_ISSUE(0, 0);
  OUT_ISSUE(32, 1);
  for (int k = 0; k < 30; k += 3) {
    BAR(); OUT_ISSUE((k + 2) * 32, 2); WAITVM(6); BAR(); OUT_COMPUTE(0);
    BAR(); OUT_ISSUE((k + 3) * 32, 0); WAITVM(6); BAR(); OUT_COMPUTE(1);
    BAR(); OUT_ISSUE((k + 4) * 32, 1); WAITVM(6); BAR(); OUT_COMPUTE(2);
  }
  WAITVM(3); BAR(); OUT_COMPUTE(0);   // stage 30
  WAITVM(0); BAR(); OUT_COMPUTE(1);   // stage 31

#pragma unroll
  for (int i = 0; i < 4; ++i)
#pragma unroll
    for (int j = 0; j < 2; ++j) {
      const int col = bn * 128 + wn + j * 16 + l16;
      const float bv = bo[col];
#pragma unroll
      for (int r = 0; r < 4; ++r) {
        const int row = bm * 64 + i * 16 + quad * 4 + r;
        out[(size_t)row * D_MODEL + col] = acc[i][j][r] + bv;
      }
    }
#undef OUT_ISSUE
#undef OUT_COMPUTE
}

// ---------------- flash attention ------------------------------------------------
// Round-2 change: KV tile 128 -> 64 keys.  LDS per block 64 KB -> 32 KB
// (2 stages x (K 8KB + V 8KB)), so 4 blocks/CU are co-resident (was 2) and the
// whole 1024-block grid fits in one occupancy round (4 blocks/CU x 4 waves =
// 16 waves/CU, 4 waves/SIMD vs 2 before).  Same total staged bytes, same
// counted-vmcnt double buffering (4 loads/thread/stage -> WAITVM(4)), same
// swizzle algebra (the old inner `sub` loop is now the tile itself).
// Epilogue overlays LDS only after an explicit __syncthreads().
__global__ void __launch_bounds__(256) attn(const unsigned short* __restrict__ Qh,
                                            const unsigned short* __restrict__ Kh,
                                            const unsigned short* __restrict__ Vt,
                                            unsigned short* __restrict__ AO) {
  __shared__ __align__(16) char smem[32768];
  // stage p: Ks = smem + p*16384         [64 key][64 dh], XOR-swizzled
  //          Vs = smem + p*16384 + 8192  [64 d][64 key],  XOR-swizzled

  const int bid = blockIdx.x;
  const int qt = bid >> 5, head = bid & 31, b = head >> 4, h = head & 15;
  const int tid = threadIdx.x;
  const int lane = tid & 63, wave = tid >> 6;
  const int wq = wave >> 1, wk = wave & 1;
  const int l31 = lane & 31, hh = lane >> 5;

  const unsigned short* Qhead = Qh + (size_t)(b * HEADS + h) * SEQ * DH;
  const unsigned short* Khead = Kh + (size_t)(b * HEADS + h) * SEQ * DH;
  const unsigned short* Vhead = Vt + (size_t)(b * HEADS + h) * DH * SEQ;

  const int qrow = qt * 64 + wq * 32 + l31;
  bf16x8 aq[4];
#pragma unroll
  for (int it = 0; it < 4; ++it)
    aq[it] = *(const bf16x8*)&Qhead[(size_t)qrow * DH + it * 16 + hh * 8];

  f32x16 oacc[2] = {};
  float lsum = 0.f;

#define ATT_STAGE(KC, P)                                                      \
  do {                                                                        \
    unsigned short* Ksp = (unsigned short*)(smem + (P) * 16384);              \
    unsigned short* Vsp = (unsigned short*)(smem + (P) * 16384 + 8192);       \
    _Pragma("unroll") for (int c = 0; c < 2; ++c) {                           \
      int s = c * 256 + tid;                                                  \
      int row = s >> 3;                                                       \
      int jb = (s & 7) ^ (row & 7);                                           \
      cp16(Khead + (size_t)((KC) * 64 + row) * DH + jb * 8, &Ksp[s * 8]);     \
    }                                                                         \
    _Pragma("unroll") for (int c = 0; c < 2; ++c) {                           \
      int s = c * 256 + tid;                                                  \
      int d = s >> 3;                                                         \
      int jb = (s & 7) ^ (d & 7);                                             \
      cp16(Vhead + (size_t)d * SEQ + (KC) * 64 + jb * 8, &Vsp[s * 8]);        \
    }                                                                         \
  } while (0)

#define ATT_COMPUTE(P)                                                        \
  do {                                                                        \
    const unsigned short* Ksp = (const unsigned short*)(smem + (P) * 16384);  \
    const unsigned short* Vsp =                                               \
        (const unsigned short*)(smem + (P) * 16384 + 8192);                   \
    __builtin_amdgcn_s_setprio(1);                                            \
    const int key = wk * 32 + l31;                                            \
    f32x16 sa = {};                                                           \
    _Pragma("unroll") for (int it = 0; it < 4; ++it) {                        \
      const int sblk = (2 * it + hh) ^ (key & 7);                             \
      bf16x8 ak = *(const bf16x8*)&Ksp[key * 64 + sblk * 8];                  \
      sa = __builtin_amdgcn_mfma_f32_32x32x16_bf16(ak, aq[it], sa, 0, 0, 0);  \
    }                                                                         \
    float p[16];                                                              \
    _Pragma("unroll") for (int r = 0; r < 16; ++r) {                          \
      p[r] = __builtin_amdgcn_exp2f(sa[r]);                                   \
      lsum += p[r];                                                           \
    }                                                                         \
    _Pragma("unroll") for (int c = 0; c < 2; ++c) {                           \
      unsigned x0 = pkbf(p[8 * c + 0], p[8 * c + 1]);                         \
      unsigned x1 = pkbf(p[8 * c + 2], p[8 * c + 3]);                         \
      unsigned y0 = pkbf(p[8 * c + 4], p[8 * c + 5]);                         \
      unsigned y1 = pkbf(p[8 * c + 6], p[8 * c + 7]);                         \
      asm("v_permlane32_swap_b32 %0, %1" : "+v"(x0), "+v"(y0));               \
      asm("v_permlane32_swap_b32 %0, %1" : "+v"(x1), "+v"(y1));               \
      union { unsigned u[4]; bf16x8 s; } pb;                                  \
      pb.u[0] = x0; pb.u[1] = x1; pb.u[2] = y0; pb.u[3] = y1;                 \
      const int K8 = wk * 4 + 2 * c + hh;                                     \
      _Pragma("unroll") for (int dh2 = 0; dh2 < 2; ++dh2) {                   \
        const int d = dh2 * 32 + l31;                                         \
        const int sv = K8 ^ (d & 7);                                          \
        bf16x8 av = *(const bf16x8*)&Vsp[d * 64 + sv * 8];                    \
        oacc[dh2] = __builtin_amdgcn_mfma_f32_32x32x16_bf16(av, pb.s,         \
                                                            oacc[dh2],       \
                                                            0, 0, 0);        \
      }                                                                       \
    }                                                                         \
    __builtin_amdgcn_s_setprio(0);                                            \
  } while (0)

  ATT_STAGE(0, 0);
  for (int kc = 0; kc < 31; ++kc) {
    BAR();                              // all waves done reading buf[(kc+1)&1]
    ATT_STAGE(kc + 1, (kc + 1) & 1);    // prefetch next tile
    WAITVM(4);                          // wait for tile kc's 4 loads only
    BAR();
    ATT_COMPUTE(kc & 1);
  }
  WAITVM(0);
  BAR();
  ATT_COMPUTE(1);                       // tile 31

  lsum += __shfl_xor(lsum, 32);

  __syncthreads();                      // all compute done; LDS free for epilogue

  float* epiF = (float*)smem;                            // [2 wq][2048]
  float* lbuf = (float*)(smem + 16384);                  // [4][32]
  unsigned short* Oq = (unsigned short*)(smem + 17408);  // [2 wq][32 q][68]

  if (l31 == lane) lbuf[wave * 32 + l31] = lsum;
  if (wk == 1) {
#pragma unroll
    for (int dh2 = 0; dh2 < 2; ++dh2)
#pragma unroll
      for (int r = 0; r < 16; ++r) {
        const int d = dh2 * 32 + (r & 3) + 8 * (r >> 2) + 4 * hh;
        epiF[wq * 2048 + d * 32 + l31] = oacc[dh2][r];
      }
  }
  __syncthreads();

  if (wk == 0) {
    const float linv = 1.0f / (lsum + lbuf[(wq * 2 + 1) * 32 + l31]);
#pragma unroll
    for (int dh2 = 0; dh2 < 2; ++dh2) {
#pragma unroll
      for (int r = 0; r < 16; r += 2) {
        const int d = dh2 * 32 + (r & 3) + 8 * (r >> 2) + 4 * hh;
        const float v0 = (oacc[dh2][r]     + epiF[wq * 2048 + d * 32 + l31]) * linv;
        const float v1 = (oacc[dh2][r + 1] + epiF[wq * 2048 + (d + 1) * 32 + l31]) * linv;
        *(unsigned*)&Oq[wq * 2176 + l31 * 68 + d] = pkbf(v0, v1);
      }
    }
  }
  __syncthreads();

  {
    const int qloc = tid >> 2, d0 = (tid & 3) * 16;
    const int base = (qloc >> 5) * 2176 + (qloc & 31) * 68 + d0;
    unsigned u[8];
#pragma unroll
    for (int i = 0; i < 8; ++i) u[i] = *(const unsigned*)&Oq[base + i * 2];
    unsigned short* dst = AO + ((size_t)(b * SEQ + qt * 64 + qloc)) * D_MODEL + h * 64 + d0;
    *(uint4*)dst       = make_uint4(u[0], u[1], u[2], u[3]);
    *(uint4*)(dst + 8) = make_uint4(u[4], u[5], u[6], u[7]);
  }
#undef ATT_STAGE
#undef ATT_COMPUTE
}

extern "C" void kernel_launch(void* const* d_in, const int* in_sizes, int n_in,
                              void* d_out, int out_size, void* d_ws, size_t ws_size,
                              hipStream_t stream) {
  const float* q  = (const float*)d_in[0];
  const float* k  = (const float*)d_in[1];
  const float* v  = (const float*)d_in[2];
  const float* Wq = (const float*)d_in[3];
  const float* bq = (const float*)d_in[4];
  const float* Wk = (const float*)d_in[5];
  const float* bk = (const float*)d_in[6];
  const float* Wv = (const float*)d_in[7];
  const float* bv = (const float*)d_in[8];
  const float* Wo = (const float*)d_in[9];
  const float* bo = (const float*)d_in[10];
  float* out = (float*)d_out;

  char* ws = (char*)d_ws;
  const size_t MB = 1ull << 20;
  unsigned short* qb  = (unsigned short*)(ws + 0 * MB);
  unsigned short* kb  = (unsigned short*)(ws + 8 * MB);
  unsigned short* vb  = (unsigned short*)(ws + 16 * MB);
  unsigned short* Wqb = (unsigned short*)(ws + 24 * MB);
  unsigned short* Wkb = (unsigned short*)(ws + 26 * MB);
  unsigned short* Wvb = (unsigned short*)(ws + 28 * MB);
  unsigned short* Wob = (unsigned short*)(ws + 30 * MB);
  unsigned short* Qh  = (unsigned short*)(ws + 32 * MB);
  unsigned short* Kh  = (unsigned short*)(ws + 40 * MB);
  unsigned short* Vt  = (unsigned short*)(ws + 48 * MB);
  unsigned short* AO  = (unsigned short*)(ws + 56 * MB);

  castall<<<16384, 256, 0, stream>>>(q, k, v, Wq, Wk, Wv, Wo,
                                     qb, kb, vb, Wqb, Wkb, Wvb, Wob);

  const float qscale = 0.125f * 1.44269504088896f;  // fold 1/sqrt(Dh) and log2(e) into Q
  qkv_gemm<<<768, 256, 0, stream>>>(qb, kb, vb, Wqb, Wkb, Wvb, bq, bk, bv,
                                    Qh, Kh, Vt, qscale);

  attn<<<1024, 256, 0, stream>>>(Qh, Kh, Vt, AO);

  out_gemm<<<512, 256, 0, stream>>>(AO, Wob, bo, out);
}

// Round 4
// 223.519 us; speedup vs baseline: 1.0524x; 1.0385x over previous
//
#include <hip/hip_runtime.h>
#include <cstdint>
#include <cstddef>

#define DEVI __device__ __forceinline__

typedef short bf16x8 __attribute__((ext_vector_type(8)));
typedef short bf16x4 __attribute__((ext_vector_type(4)));
typedef float f32x4 __attribute__((ext_vector_type(4)));
typedef float f32x16 __attribute__((ext_vector_type(16)));
typedef unsigned short u16x4 __attribute__((ext_vector_type(4)));

constexpr int D_MODEL = 1024;
constexpr int HEADS = 16;
constexpr int DH = 64;
constexpr int SEQ = 2048;
constexpr int KDIM = 1024;

DEVI unsigned short f2bf(float f) {
  union { float f; unsigned u; } v; v.f = f;
  unsigned r = v.u + 0x7fffu + ((v.u >> 16) & 1u);
  return (unsigned short)(r >> 16);
}

// pack two fp32 -> two TRUNCATED bf16 in one dword (a = low16, b = high16)
DEVI unsigned pkbf(float a, float b) {
  return __builtin_amdgcn_perm(__float_as_uint(b), __float_as_uint(a), 0x07060302u);
}

DEVI void cp16(const void* g, void* l) {
  __builtin_amdgcn_global_load_lds(
      (const __attribute__((address_space(1))) void*)g,
      (__attribute__((address_space(3))) void*)l, 16, 0, 0);
}

#define BAR()        asm volatile("s_barrier" ::: "memory")
#define WAITVM(n)    asm volatile("s_waitcnt vmcnt(" #n ")" ::: "memory")

// ---------------- fused fp32 -> bf16 cast for all 7 tensors ----------------
__global__ void __launch_bounds__(256) castall(
    const float* __restrict__ q, const float* __restrict__ k, const float* __restrict__ v,
    const float* __restrict__ Wq, const float* __restrict__ Wk,
    const float* __restrict__ Wv, const float* __restrict__ Wo,
    unsigned short* __restrict__ qb, unsigned short* __restrict__ kb, unsigned short* __restrict__ vb,
    unsigned short* __restrict__ Wqb, unsigned short* __restrict__ Wkb,
    unsigned short* __restrict__ Wvb, unsigned short* __restrict__ Wob) {
  int bid = blockIdx.x;
  const float* s; unsigned short* d; int off;
  if (bid < 12288) {
    int w = bid >> 12; off = bid & 4095;
    s = (w == 0) ? q : ((w == 1) ? k : v);
    d = (w == 0) ? qb : ((w == 1) ? kb : vb);
  } else {
    int w = (bid - 12288) >> 10; off = bid & 1023;
    s = (w == 0) ? Wq : ((w == 1) ? Wk : ((w == 2) ? Wv : Wo));
    d = (w == 0) ? Wqb : ((w == 1) ? Wkb : ((w == 2) ? Wvb : Wob));
  }
  int i = (off * 256 + threadIdx.x) * 4;
  float4 x = *(const float4*)(s + i);
  u16x4 o; o[0] = f2bf(x.x); o[1] = f2bf(x.y); o[2] = f2bf(x.z); o[3] = f2bf(x.w);
  *(u16x4*)(d + i) = o;
}

// ---------------- QKV projection: 128x128 tile, triple-buffered, XCD-local ----------
__global__ void __launch_bounds__(256) qkv_gemm(
    const unsigned short* __restrict__ qb, const unsigned short* __restrict__ kb,
    const unsigned short* __restrict__ vb,
    const unsigned short* __restrict__ Wqb, const unsigned short* __restrict__ Wkb,
    const unsigned short* __restrict__ Wvb,
    const float* __restrict__ bq, const float* __restrict__ bk, const float* __restrict__ bv,
    unsigned short* __restrict__ Qh, unsigned short* __restrict__ Kh,
    unsigned short* __restrict__ Vt, float qscale) {
  __shared__ unsigned short As[3][128 * 32];
  __shared__ unsigned short Bs[3][128 * 32];
  const int bid = blockIdx.x, seg = bid >> 8, inner = bid & 255;
  const int bm = inner & 31, bn = inner >> 5;          // XCD-local swizzle
  const unsigned short* A = (seg == 0) ? qb : ((seg == 1) ? kb : vb);
  const unsigned short* W = (seg == 0) ? Wqb : ((seg == 1) ? Wkb : Wvb);
  const float* bias = (seg == 0) ? bq : ((seg == 1) ? bk : bv);
  unsigned short* O = (seg == 0) ? Qh : ((seg == 1) ? Kh : Vt);
  const float oscale = (seg == 0) ? qscale : 1.0f;
  const int mode = (seg == 2) ? 1 : 0;

  const int tid = threadIdx.x, lane = tid & 63, wave = tid >> 6;
  const int l16 = lane & 15, quad = lane >> 4;
  const int wm = (wave >> 1) * 64, wn = (wave & 1) * 64;
  const int sw = (l16 >> 1) & 3;
  f32x4 acc[4][4] = {};

  const int r0 = tid >> 2, p0 = tid & 3;
  const int c0 = (p0 ^ ((r0 >> 1) & 3)) * 8;
  const int r1 = (256 + tid) >> 2;
  const int c1 = (p0 ^ ((r1 >> 1) & 3)) * 8;
  const unsigned short* Arow0 = A + (size_t)(bm * 128 + r0) * KDIM + c0;
  const unsigned short* Arow1 = A + (size_t)(bm * 128 + r1) * KDIM + c1;
  const unsigned short* Wrow0 = W + (size_t)(bn * 128 + r0) * KDIM + c0;
  const unsigned short* Wrow1 = W + (size_t)(bn * 128 + r1) * KDIM + c1;

#define QKV_ISSUE(K0, P)                                    \
  do {                                                      \
    cp16(Arow0 + (K0), &As[P][tid * 8]);                    \
    cp16(Arow1 + (K0), &As[P][(256 + tid) * 8]);            \
    cp16(Wrow0 + (K0), &Bs[P][tid * 8]);                    \
    cp16(Wrow1 + (K0), &Bs[P][(256 + tid) * 8]);            \
  } while (0)

#define QKV_COMPUTE(P)                                                             \
  do {                                                                             \
    bf16x8 af[4], bfr[4];                                                          \
    _Pragma("unroll") for (int t = 0; t < 4; ++t)                                  \
        af[t] = *(const bf16x8*)&As[P][(wm + t * 16 + l16) * 32 + ((quad ^ sw) * 8)]; \
    _Pragma("unroll") for (int t = 0; t < 4; ++t)                                  \
        bfr[t] = *(const bf16x8*)&Bs[P][(wn + t * 16 + l16) * 32 + ((quad ^ sw) * 8)]; \
    _Pragma("unroll") for (int i = 0; i < 4; ++i)                                  \
        _Pragma("unroll") for (int j = 0; j < 4; ++j)                              \
            acc[i][j] = __builtin_amdgcn_mfma_f32_16x16x32_bf16(af[i], bfr[j],     \
                                                                acc[i][j], 0, 0, 0); \
  } while (0)

  QKV_ISSUE(0, 0);
  QKV_ISSUE(32, 1);
  for (int k = 0; k < 30; k += 3) {
    BAR(); QKV_ISSUE((k + 2) * 32, 2); WAITVM(8); BAR(); QKV_COMPUTE(0);
    BAR(); QKV_ISSUE((k + 3) * 32, 0); WAITVM(8); BAR(); QKV_COMPUTE(1);
    BAR(); QKV_ISSUE((k + 4) * 32, 1); WAITVM(8); BAR(); QKV_COMPUTE(2);
  }
  WAITVM(4); BAR(); QKV_COMPUTE(0);   // stage 30
  WAITVM(0); BAR(); QKV_COMPUTE(1);   // stage 31

#pragma unroll
  for (int i = 0; i < 4; ++i) {
#pragma unroll
    for (int j = 0; j < 4; ++j) {
      const int col = bn * 128 + wn + j * 16 + l16;
      const float bv = bias[col];
#pragma unroll
      for (int r = 0; r < 4; ++r) {
        const int row = bm * 128 + wm + i * 16 + quad * 4 + r;
        const float val = (acc[i][j][r] + bv) * oscale;
        const int b = row >> 11, s = row & (SEQ - 1);
        const int h = col >> 6, d = col & (DH - 1);
        size_t idx;
        if (mode == 0) idx = ((size_t)(b * HEADS + h) * SEQ + s) * DH + d;
        else           idx = ((size_t)(b * HEADS + h) * DH + d) * SEQ + s;
        O[idx] = f2bf(val);
      }
    }
  }
#undef QKV_ISSUE
#undef QKV_COMPUTE
}

// ---------------- output projection: 64x128 tile, triple-buffered, XCD-local ------
__global__ void __launch_bounds__(256) out_gemm(const unsigned short* __restrict__ AO,
                                                const unsigned short* __restrict__ Wob,
                                                const float* __restrict__ bo,
                                                float* __restrict__ out) {
  __shared__ unsigned short As[3][64 * 32];
  __shared__ unsigned short Bs[3][128 * 32];
  const int bid = blockIdx.x, bm = bid & 63, bn = bid >> 6;
  const int tid = threadIdx.x, lane = tid & 63, wave = tid >> 6;
  const int l16 = lane & 15, quad = lane >> 4;
  const int wn = wave * 32;
  const int sw = (l16 >> 1) & 3;
  f32x4 acc[4][2] = {};

  const int ra = tid >> 2, pa = tid & 3;
  const int ca = (pa ^ ((ra >> 1) & 3)) * 8;
  const int r1 = (256 + tid) >> 2;
  const int c1 = (pa ^ ((r1 >> 1) & 3)) * 8;
  const unsigned short* Arow  = AO + (size_t)(bm * 64 + ra) * KDIM + ca;
  const unsigned short* Wrow0 = Wob + (size_t)(bn * 128 + ra) * KDIM + ca;
  const unsigned short* Wrow1 = Wob + (size_t)(bn * 128 + r1) * KDIM + c1;

#define OUT_ISSUE(K0, P)                                    \
  do {                                                      \
    cp16(Arow + (K0), &As[P][tid * 8]);                     \
    cp16(Wrow0 + (K0), &Bs[P][tid * 8]);                    \
    cp16(Wrow1 + (K0), &Bs[P][(256 + tid) * 8]);            \
  } while (0)

#define OUT_COMPUTE(P)                                                             \
  do {                                                                             \
    bf16x8 af[4], bfr[2];                                                          \
    _Pragma("unroll") for (int t = 0; t < 4; ++t)                                  \
        af[t] = *(const bf16x8*)&As[P][(t * 16 + l16) * 32 + ((quad ^ sw) * 8)];   \
    _Pragma("unroll") for (int u = 0; u < 2; ++u)                                  \
        bfr[u] = *(const bf16x8*)&Bs[P][(wn + u * 16 + l16) * 32 + ((quad ^ sw) * 8)]; \
    _Pragma("unroll") for (int i = 0; i < 4; ++i)                                  \
        _Pragma("unroll") for (int j = 0; j < 2; ++j)                              \
            acc[i][j] = __builtin_amdgcn_mfma_f32_16x16x32_bf16(af[i], bfr[j],     \
                                                                acc[i][j], 0, 0, 0); \
  } while (0)

  OUT_ISSUE(0, 0);
  OUT_ISSUE(32, 1);
  for (int k = 0; k < 30; k += 3) {
    BAR(); OUT_ISSUE((k + 2) * 32, 2); WAITVM(6); BAR(); OUT_COMPUTE(0);
    BAR(); OUT_ISSUE((k + 3) * 32, 0); WAITVM(6); BAR(); OUT_COMPUTE(1);
    BAR(); OUT_ISSUE((k + 4) * 32, 1); WAITVM(6); BAR(); OUT_COMPUTE(2);
  }
  WAITVM(3); BAR(); OUT_COMPUTE(0);   // stage 30
  WAITVM(0); BAR(); OUT_COMPUTE(1);   // stage 31

#pragma unroll
  for (int i = 0; i < 4; ++i)
#pragma unroll
    for (int j = 0; j < 2; ++j) {
      const int col = bn * 128 + wn + j * 16 + l16;
      const float bv = bo[col];
#pragma unroll
      for (int r = 0; r < 4; ++r) {
        const int row = bm * 64 + i * 16 + quad * 4 + r;
        out[(size_t)row * D_MODEL + col] = acc[i][j][r] + bv;
      }
    }
#undef OUT_ISSUE
#undef OUT_COMPUTE
}

// ---------------- flash attention ------------------------------------------------
// Round-4: two 32-row q-sets per wave (block = 128 q-rows, grid 512) so every
// ds_read_b128 K/V fragment feeds TWO MFMAs with independent accumulators
// (LDS-read cycles per MFMA halve; PV gets 2x ILP).  Differences vs the failed
// round-3 attempt:
//  * Pipeline uses one vmcnt(0) per tile (WAITVM(0); BAR; STAGE(next);
//    COMPUTE(cur); BAR) instead of counted vmcnt(8).  Counted vmcnt silently
//    breaks if the compiler spills or rematerializes the loop-invariant Q
//    loads inside the loop under high VGPR pressure (any stray vmem op skews
//    the count) -- the suspected round-3 failure.  vmcnt(0) is robust to any
//    extra vmem traffic, and the next tile's loads are still in flight for
//    the whole compute phase.
//  * Softmax runs sequentially per q-set (one sa/p live at a time) to cut
//    peak register pressure; ak[4]/av remain register-shared across sets.
//  * __launch_bounds__(256,1): no occupancy-driven VGPR cap (LDS caps us at
//    2 blocks/CU regardless).
__global__ void __launch_bounds__(256, 1) attn(const unsigned short* __restrict__ Qh,
                                               const unsigned short* __restrict__ Kh,
                                               const unsigned short* __restrict__ Vt,
                                               unsigned short* __restrict__ AO) {
  __shared__ __align__(16) char smem[65536];
  // stage p: Ks = smem + p*32768          [128 key][64 dh], XOR-swizzled
  //          Vs = smem + p*32768 + 16384  [64 d][128 key],  XOR-swizzled

  const int bid = blockIdx.x;
  const int qt = bid >> 5, head = bid & 31, b = head >> 4, h = head & 15;
  const int tid = threadIdx.x;
  const int lane = tid & 63, wave = tid >> 6;
  const int wq = wave >> 1, wk = wave & 1;
  const int l31 = lane & 31, hh = lane >> 5;

  const unsigned short* Qhead = Qh + (size_t)(b * HEADS + h) * SEQ * DH;
  const unsigned short* Khead = Kh + (size_t)(b * HEADS + h) * SEQ * DH;
  const unsigned short* Vhead = Vt + (size_t)(b * HEADS + h) * DH * SEQ;

  const int qrow0 = qt * 128 + wq * 64 + l31;   // q-set 0; q-set 1 = +32
  bf16x8 aq0[4], aq1[4];
#pragma unroll
  for (int it = 0; it < 4; ++it) {
    aq0[it] = *(const bf16x8*)&Qhead[(size_t)qrow0 * DH + it * 16 + hh * 8];
    aq1[it] = *(const bf16x8*)&Qhead[(size_t)(qrow0 + 32) * DH + it * 16 + hh * 8];
  }

  f32x16 oacc0[2] = {}, oacc1[2] = {};
  float lsum0 = 0.f, lsum1 = 0.f;

#define ATT_STAGE(KC, P)                                                      \
  do {                                                                        \
    unsigned short* Ksp = (unsigned short*)(smem + (P) * 32768);              \
    unsigned short* Vsp = (unsigned short*)(smem + (P) * 32768 + 16384);      \
    _Pragma("unroll") for (int c = 0; c < 4; ++c) {                           \
      int s = c * 256 + tid;                                                  \
      int row = s >> 3, pblk = s & 7;                                         \
      int jb = pblk ^ (row & 7);                                              \
      cp16(Khead + (size_t)((KC) * 128 + row) * DH + jb * 8, &Ksp[s * 8]);    \
    }                                                                         \
    _Pragma("unroll") for (int c = 0; c < 4; ++c) {                           \
      int s = c * 256 + tid;                                                  \
      int d = s >> 4, pblk = s & 15;                                          \
      int jb = pblk ^ (d & 7);                                                \
      cp16(Vhead + (size_t)d * SEQ + (KC) * 128 + jb * 8, &Vsp[s * 8]);       \
    }                                                                         \
  } while (0)

#define ATT_SOFTMAX(SA, PB, LSUM)                                             \
  do {                                                                        \
    float p[16];                                                              \
    _Pragma("unroll") for (int r = 0; r < 16; ++r) {                          \
      p[r] = __builtin_amdgcn_exp2f((SA)[r]);                                 \
      (LSUM) += p[r];                                                         \
    }                                                                         \
    _Pragma("unroll") for (int c = 0; c < 2; ++c) {                           \
      unsigned x0 = pkbf(p[8 * c + 0], p[8 * c + 1]);                         \
      unsigned x1 = pkbf(p[8 * c + 2], p[8 * c + 3]);                         \
      unsigned y0 = pkbf(p[8 * c + 4], p[8 * c + 5]);                         \
      unsigned y1 = pkbf(p[8 * c + 6], p[8 * c + 7]);                         \
      asm("v_permlane32_swap_b32 %0, %1" : "+v"(x0), "+v"(y0));               \
      asm("v_permlane32_swap_b32 %0, %1" : "+v"(x1), "+v"(y1));               \
      union { unsigned u[4]; bf16x8 s; } pbu;                                 \
      pbu.u[0] = x0; pbu.u[1] = x1; pbu.u[2] = y0; pbu.u[3] = y1;             \
      (PB)[c] = pbu.s;                                                        \
    }                                                                         \
  } while (0)

#define ATT_COMPUTE(P)                                                        \
  do {                                                                        \
    const unsigned short* Ksp = (const unsigned short*)(smem + (P) * 32768);  \
    const unsigned short* Vsp =                                               \
        (const unsigned short*)(smem + (P) * 32768 + 16384);                  \
    __builtin_amdgcn_s_setprio(1);                                            \
    _Pragma("unroll") for (int sub = 0; sub < 2; ++sub) {                     \
      const int key = sub * 64 + wk * 32 + l31;                               \
      bf16x8 ak[4];                                                           \
      _Pragma("unroll") for (int it = 0; it < 4; ++it) {                      \
        const int sblk = (2 * it + hh) ^ (key & 7);                           \
        ak[it] = *(const bf16x8*)&Ksp[key * 64 + sblk * 8];                   \
      }                                                                       \
      bf16x8 pb0[2], pb1[2];                                                  \
      {                                                                       \
        f32x16 sa = {};                                                       \
        _Pragma("unroll") for (int it = 0; it < 4; ++it)                      \
          sa = __builtin_amdgcn_mfma_f32_32x32x16_bf16(ak[it], aq0[it], sa,   \
                                                       0, 0, 0);              \
        ATT_SOFTMAX(sa, pb0, lsum0);                                          \
      }                                                                       \
      {                                                                       \
        f32x16 sa = {};                                                       \
        _Pragma("unroll") for (int it = 0; it < 4; ++it)                      \
          sa = __builtin_amdgcn_mfma_f32_32x32x16_bf16(ak[it], aq1[it], sa,   \
                                                       0, 0, 0);              \
        ATT_SOFTMAX(sa, pb1, lsum1);                                          \
      }                                                                       \
      _Pragma("unroll") for (int c = 0; c < 2; ++c) {                         \
        const int K8 = sub * 8 + wk * 4 + 2 * c + hh;                         \
        _Pragma("unroll") for (int dh2 = 0; dh2 < 2; ++dh2) {                 \
          const int d = dh2 * 32 + l31;                                       \
          const int sv = K8 ^ (d & 7);                                        \
          bf16x8 av = *(const bf16x8*)&Vsp[d * 128 + sv * 8];                 \
          oacc0[dh2] = __builtin_amdgcn_mfma_f32_32x32x16_bf16(av, pb0[c],    \
                                                               oacc0[dh2],   \
                                                               0, 0, 0);     \
          oacc1[dh2] = __builtin_amdgcn_mfma_f32_32x32x16_bf16(av, pb1[c],    \
                                                               oacc1[dh2],   \
                                                               0, 0, 0);     \
        }                                                                     \
      }                                                                       \
    }                                                                         \
    __builtin_amdgcn_s_setprio(0);                                            \
  } while (0)

  ATT_STAGE(0, 0);
  for (int kc = 0; kc < 16; ++kc) {
    WAITVM(0);                          // tile kc's loads (and ANY stray vmem) done
    BAR();                              // all waves' stage-kc data visible
    if (kc < 15) ATT_STAGE(kc + 1, (kc + 1) & 1);  // next tile flies during compute
    ATT_COMPUTE(kc & 1);
    BAR();                              // all waves done reading buf kc&1
  }

  lsum0 += __shfl_xor(lsum0, 32);
  lsum1 += __shfl_xor(lsum1, 32);

  // epilogue scratch overlays stage 0 (last read at kc=14; final BAR passed)
  float* epiF = (float*)smem;                            // [2 wq][2048]
  float* lbuf = (float*)(smem + 16384);                  // [4][32]
  unsigned short* Oq = (unsigned short*)(smem + 17408);  // [2 wq][32 q][68]

#define ATT_EPI(OACC, LSUM, SET)                                              \
  do {                                                                        \
    if (lane < 32) lbuf[wave * 32 + l31] = (LSUM);                            \
    if (wk == 1) {                                                            \
      _Pragma("unroll") for (int dh2 = 0; dh2 < 2; ++dh2)                     \
        _Pragma("unroll") for (int r = 0; r < 16; ++r) {                      \
          const int d = dh2 * 32 + (r & 3) + 8 * (r >> 2) + 4 * hh;           \
          epiF[wq * 2048 + d * 32 + l31] = (OACC)[dh2][r];                    \
        }                                                                     \
    }                                                                         \
    __syncthreads();                                                          \
    if (wk == 0) {                                                            \
      const float linv = 1.0f / ((LSUM) + lbuf[(wq * 2 + 1) * 32 + l31]);     \
      _Pragma("unroll") for (int dh2 = 0; dh2 < 2; ++dh2) {                   \
        _Pragma("unroll") for (int r = 0; r < 16; r += 2) {                   \
          const int d = dh2 * 32 + (r & 3) + 8 * (r >> 2) + 4 * hh;           \
          const float v0 =                                                    \
              ((OACC)[dh2][r] + epiF[wq * 2048 + d * 32 + l31]) * linv;       \
          const float v1 =                                                    \
              ((OACC)[dh2][r + 1] + epiF[wq * 2048 + (d + 1) * 32 + l31]) *   \
              linv;                                                           \
          *(unsigned*)&Oq[wq * 2176 + l31 * 68 + d] = pkbf(v0, v1);           \
        }                                                                     \
      }                                                                       \
    }                                                                         \
    __syncthreads();                                                          \
    {                                                                         \
      const int qloc = tid >> 2, d0 = (tid & 3) * 16;                         \
      const int base = (qloc >> 5) * 2176 + (qloc & 31) * 68 + d0;            \
      unsigned u[8];                                                          \
      _Pragma("unroll") for (int i = 0; i < 8; ++i)                           \
        u[i] = *(const unsigned*)&Oq[base + i * 2];                           \
      const int row = qt * 128 + (qloc >> 5) * 64 + (SET) * 32 + (qloc & 31); \
      unsigned short* dst =                                                   \
          AO + ((size_t)(b * SEQ + row)) * D_MODEL + h * 64 + d0;             \
      *(uint4*)dst       = make_uint4(u[0], u[1], u[2], u[3]);                \
      *(uint4*)(dst + 8) = make_uint4(u[4], u[5], u[6], u[7]);                \
    }                                                                         \
  } while (0)

  ATT_EPI(oacc0, lsum0, 0);
  __syncthreads();
  ATT_EPI(oacc1, lsum1, 1);

#undef ATT_STAGE
#undef ATT_SOFTMAX
#undef ATT_COMPUTE
#undef ATT_EPI
}

extern "C" void kernel_launch(void* const* d_in, const int* in_sizes, int n_in,
                              void* d_out, int out_size, void* d_ws, size_t ws_size,
                              hipStream_t stream) {
  const float* q  = (const float*)d_in[0];
  const float* k  = (const float*)d_in[1];
  const float* v  = (const float*)d_in[2];
  const float* Wq = (const float*)d_in[3];
  const float* bq = (const float*)d_in[4];
  const float* Wk = (const float*)d_in[5];
  const float* bk = (const float*)d_in[6];
  const float* Wv = (const float*)d_in[7];
  const float* bv = (const float*)d_in[8];
  const float* Wo = (const float*)d_in[9];
  const float* bo = (const float*)d_in[10];
  float* out = (float*)d_out;

  char* ws = (char*)d_ws;
  const size_t MB = 1ull << 20;
  unsigned short* qb  = (unsigned short*)(ws + 0 * MB);
  unsigned short* kb  = (unsigned short*)(ws + 8 * MB);
  unsigned short* vb  = (unsigned short*)(ws + 16 * MB);
  unsigned short* Wqb = (unsigned short*)(ws + 24 * MB);
  unsigned short* Wkb = (unsigned short*)(ws + 26 * MB);
  unsigned short* Wvb = (unsigned short*)(ws + 28 * MB);
  unsigned short* Wob = (unsigned short*)(ws + 30 * MB);
  unsigned short* Qh  = (unsigned short*)(ws + 32 * MB);
  unsigned short* Kh  = (unsigned short*)(ws + 40 * MB);
  unsigned short* Vt  = (unsigned short*)(ws + 48 * MB);
  unsigned short* AO  = (unsigned short*)(ws + 56 * MB);

  castall<<<16384, 256, 0, stream>>>(q, k, v, Wq, Wk, Wv, Wo,
                                     qb, kb, vb, Wqb, Wkb, Wvb, Wob);

  const float qscale = 0.125f * 1.44269504088896f;  // fold 1/sqrt(Dh) and log2(e) into Q
  qkv_gemm<<<768, 256, 0, stream>>>(qb, kb, vb, Wqb, Wkb, Wvb, bq, bk, bv,
                                    Qh, Kh, Vt, qscale);

  attn<<<512, 256, 0, stream>>>(Qh, Kh, Vt, AO);

  out_gemm<<<512, 256, 0, stream>>>(AO, Wob, bo, out);
}

// Round 7
// 222.291 us; speedup vs baseline: 1.0582x; 1.0055x over previous
//
#include <hip/hip_runtime.h>
#include <cstdint>
#include <cstddef>

#define DEVI __device__ __forceinline__

typedef short bf16x8 __attribute__((ext_vector_type(8)));
typedef short bf16x4 __attribute__((ext_vector_type(4)));
typedef float f32x4 __attribute__((ext_vector_type(4)));
typedef float f32x16 __attribute__((ext_vector_type(16)));
typedef unsigned short u16x4 __attribute__((ext_vector_type(4)));

constexpr int D_MODEL = 1024;
constexpr int HEADS = 16;
constexpr int DH = 64;
constexpr int SEQ = 2048;
constexpr int KDIM = 1024;

DEVI unsigned short f2bf(float f) {
  union { float f; unsigned u; } v; v.f = f;
  unsigned r = v.u + 0x7fffu + ((v.u >> 16) & 1u);
  return (unsigned short)(r >> 16);
}

// pack two fp32 -> two TRUNCATED bf16 in one dword (a = low16, b = high16)
DEVI unsigned pkbf(float a, float b) {
  return __builtin_amdgcn_perm(__float_as_uint(b), __float_as_uint(a), 0x07060302u);
}

DEVI void cp16(const void* g, void* l) {
  __builtin_amdgcn_global_load_lds(
      (const __attribute__((address_space(1))) void*)g,
      (__attribute__((address_space(3))) void*)l, 16, 0, 0);
}

#define BAR()        asm volatile("s_barrier" ::: "memory")
#define WAITVM(n)    asm volatile("s_waitcnt vmcnt(" #n ")" ::: "memory")

// ---------------- fused fp32 -> bf16 cast for all 7 tensors ----------------
__global__ void __launch_bounds__(256) castall(
    const float* __restrict__ q, const float* __restrict__ k, const float* __restrict__ v,
    const float* __restrict__ Wq, const float* __restrict__ Wk,
    const float* __restrict__ Wv, const float* __restrict__ Wo,
    unsigned short* __restrict__ qb, unsigned short* __restrict__ kb, unsigned short* __restrict__ vb,
    unsigned short* __restrict__ Wqb, unsigned short* __restrict__ Wkb,
    unsigned short* __restrict__ Wvb, unsigned short* __restrict__ Wob) {
  int bid = blockIdx.x;
  const float* s; unsigned short* d; int off;
  if (bid < 12288) {
    int w = bid >> 12; off = bid & 4095;
    s = (w == 0) ? q : ((w == 1) ? k : v);
    d = (w == 0) ? qb : ((w == 1) ? kb : vb);
  } else {
    int w = (bid - 12288) >> 10; off = bid & 1023;
    s = (w == 0) ? Wq : ((w == 1) ? Wk : ((w == 2) ? Wv : Wo));
    d = (w == 0) ? Wqb : ((w == 1) ? Wkb : ((w == 2) ? Wvb : Wob));
  }
  int i = (off * 256 + threadIdx.x) * 4;
  float4 x = *(const float4*)(s + i);
  u16x4 o; o[0] = f2bf(x.x); o[1] = f2bf(x.y); o[2] = f2bf(x.z); o[3] = f2bf(x.w);
  *(u16x4*)(d + i) = o;
}

// ---------------- QKV projection: 128x128 tile, triple-buffered, XCD-local ----------
__global__ void __launch_bounds__(256) qkv_gemm(
    const unsigned short* __restrict__ qb, const unsigned short* __restrict__ kb,
    const unsigned short* __restrict__ vb,
    const unsigned short* __restrict__ Wqb, const unsigned short* __restrict__ Wkb,
    const unsigned short* __restrict__ Wvb,
    const float* __restrict__ bq, const float* __restrict__ bk, const float* __restrict__ bv,
    unsigned short* __restrict__ Qh, unsigned short* __restrict__ Kh,
    unsigned short* __restrict__ Vt, float qscale) {
  __shared__ unsigned short As[3][128 * 32];
  __shared__ unsigned short Bs[3][128 * 32];
  const int bid = blockIdx.x, seg = bid >> 8, inner = bid & 255;
  const int bm = inner & 31, bn = inner >> 5;          // XCD-local swizzle
  const unsigned short* A = (seg == 0) ? qb : ((seg == 1) ? kb : vb);
  const unsigned short* W = (seg == 0) ? Wqb : ((seg == 1) ? Wkb : Wvb);
  const float* bias = (seg == 0) ? bq : ((seg == 1) ? bk : bv);
  unsigned short* O = (seg == 0) ? Qh : ((seg == 1) ? Kh : Vt);
  const float oscale = (seg == 0) ? qscale : 1.0f;
  const int mode = (seg == 2) ? 1 : 0;

  const int tid = threadIdx.x, lane = tid & 63, wave = tid >> 6;
  const int l16 = lane & 15, quad = lane >> 4;
  const int wm = (wave >> 1) * 64, wn = (wave & 1) * 64;
  const int sw = (l16 >> 1) & 3;
  f32x4 acc[4][4] = {};

  const int r0 = tid >> 2, p0 = tid & 3;
  const int c0 = (p0 ^ ((r0 >> 1) & 3)) * 8;
  const int r1 = (256 + tid) >> 2;
  const int c1 = (p0 ^ ((r1 >> 1) & 3)) * 8;
  const unsigned short* Arow0 = A + (size_t)(bm * 128 + r0) * KDIM + c0;
  const unsigned short* Arow1 = A + (size_t)(bm * 128 + r1) * KDIM + c1;
  const unsigned short* Wrow0 = W + (size_t)(bn * 128 + r0) * KDIM + c0;
  const unsigned short* Wrow1 = W + (size_t)(bn * 128 + r1) * KDIM + c1;

#define QKV_ISSUE(K0, P)                                    \
  do {                                                      \
    cp16(Arow0 + (K0), &As[P][tid * 8]);                    \
    cp16(Arow1 + (K0), &As[P][(256 + tid) * 8]);            \
    cp16(Wrow0 + (K0), &Bs[P][tid * 8]);                    \
    cp16(Wrow1 + (K0), &Bs[P][(256 + tid) * 8]);            \
  } while (0)

#define QKV_COMPUTE(P)                                                             \
  do {                                                                             \
    bf16x8 af[4], bfr[4];                                                          \
    _Pragma("unroll") for (int t = 0; t < 4; ++t)                                  \
        af[t] = *(const bf16x8*)&As[P][(wm + t * 16 + l16) * 32 + ((quad ^ sw) * 8)]; \
    _Pragma("unroll") for (int t = 0; t < 4; ++t)                                  \
        bfr[t] = *(const bf16x8*)&Bs[P][(wn + t * 16 + l16) * 32 + ((quad ^ sw) * 8)]; \
    _Pragma("unroll") for (int i = 0; i < 4; ++i)                                  \
        _Pragma("unroll") for (int j = 0; j < 4; ++j)                              \
            acc[i][j] = __builtin_amdgcn_mfma_f32_16x16x32_bf16(af[i], bfr[j],     \
                                                                acc[i][j], 0, 0, 0); \
  } while (0)

  QKV_ISSUE(0, 0);
  QKV_ISSUE(32, 1);
  for (int k = 0; k < 30; k += 3) {
    BAR(); QKV_ISSUE((k + 2) * 32, 2); WAITVM(8); BAR(); QKV_COMPUTE(0);
    BAR(); QKV_ISSUE((k + 3) * 32, 0); WAITVM(8); BAR(); QKV_COMPUTE(1);
    BAR(); QKV_ISSUE((k + 4) * 32, 1); WAITVM(8); BAR(); QKV_COMPUTE(2);
  }
  WAITVM(4); BAR(); QKV_COMPUTE(0);   // stage 30
  WAITVM(0); BAR(); QKV_COMPUTE(1);   // stage 31

#pragma unroll
  for (int i = 0; i < 4; ++i) {
#pragma unroll
    for (int j = 0; j < 4; ++j) {
      const int col = bn * 128 + wn + j * 16 + l16;
      const float bv = bias[col];
#pragma unroll
      for (int r = 0; r < 4; ++r) {
        const int row = bm * 128 + wm + i * 16 + quad * 4 + r;
        const float val = (acc[i][j][r] + bv) * oscale;
        const int b = row >> 11, s = row & (SEQ - 1);
        const int h = col >> 6, d = col & (DH - 1);
        size_t idx;
        if (mode == 0) idx = ((size_t)(b * HEADS + h) * SEQ + s) * DH + d;
        else           idx = ((size_t)(b * HEADS + h) * DH + d) * SEQ + s;
        O[idx] = f2bf(val);
      }
    }
  }
#undef QKV_ISSUE
#undef QKV_COMPUTE
}

// ---------------- output projection: NOW 128x128 tile (verified qkv structure) ----
// Verbatim instantiation of qkv_gemm's triple-buffered 128x128 pipeline; only
// the epilogue differs (plain row-major fp32 + bias, no head-split, no cast).
// Grid 256 = 32 bm x 8 bn; blocks sharing an A-tile are congruent mod 8 ->
// same XCD (A-tile reuse stays in one L2).
__global__ void __launch_bounds__(256) out_gemm(const unsigned short* __restrict__ AO,
                                                const unsigned short* __restrict__ Wob,
                                                const float* __restrict__ bo,
                                                float* __restrict__ out) {
  __shared__ unsigned short As[3][128 * 32];
  __shared__ unsigned short Bs[3][128 * 32];
  const int bid = blockIdx.x, bm = bid & 31, bn = bid >> 5;
  const int tid = threadIdx.x, lane = tid & 63, wave = tid >> 6;
  const int l16 = lane & 15, quad = lane >> 4;
  const int wm = (wave >> 1) * 64, wn = (wave & 1) * 64;
  const int sw = (l16 >> 1) & 3;
  f32x4 acc[4][4] = {};

  const int r0 = tid >> 2, p0 = tid & 3;
  const int c0 = (p0 ^ ((r0 >> 1) & 3)) * 8;
  const int r1 = (256 + tid) >> 2;
  const int c1 = (p0 ^ ((r1 >> 1) & 3)) * 8;
  const unsigned short* Arow0 = AO + (size_t)(bm * 128 + r0) * KDIM + c0;
  const unsigned short* Arow1 = AO + (size_t)(bm * 128 + r1) * KDIM + c1;
  const unsigned short* Wrow0 = Wob + (size_t)(bn * 128 + r0) * KDIM + c0;
  const unsigned short* Wrow1 = Wob + (size_t)(bn * 128 + r1) * KDIM + c1;

#define OUT_ISSUE(K0, P)                                    \
  do {                                                      \
    cp16(Arow0 + (K0), &As[P][tid * 8]);                    \
    cp16(Arow1 + (K0), &As[P][(256 + tid) * 8]);            \
    cp16(Wrow0 + (K0), &Bs[P][tid * 8]);                    \
    cp16(Wrow1 + (K0), &Bs[P][(256 + tid) * 8]);            \
  } while (0)

#define OUT_COMPUTE(P)                                                             \
  do {                                                                             \
    bf16x8 af[4], bfr[4];                                                          \
    _Pragma("unroll") for (int t = 0; t < 4; ++t)                                  \
        af[t] = *(const bf16x8*)&As[P][(wm + t * 16 + l16) * 32 + ((quad ^ sw) * 8)]; \
    _Pragma("unroll") for (int t = 0; t < 4; ++t)                                  \
        bfr[t] = *(const bf16x8*)&Bs[P][(wn + t * 16 + l16) * 32 + ((quad ^ sw) * 8)]; \
    _Pragma("unroll") for (int i = 0; i < 4; ++i)                                  \
        _Pragma("unroll") for (int j = 0; j < 4; ++j)                              \
            acc[i][j] = __builtin_amdgcn_mfma_f32_16x16x32_bf16(af[i], bfr[j],     \
                                                                acc[i][j], 0, 0, 0); \
  } while (0)

  OUT_ISSUE(0, 0);
  OUT_ISSUE(32, 1);
  for (int k = 0; k < 30; k += 3) {
    BAR(); OUT_ISSUE((k + 2) * 32, 2); WAITVM(8); BAR(); OUT_COMPUTE(0);
    BAR(); OUT_ISSUE((k + 3) * 32, 0); WAITVM(8); BAR(); OUT_COMPUTE(1);
    BAR(); OUT_ISSUE((k + 4) * 32, 1); WAITVM(8); BAR(); OUT_COMPUTE(2);
  }
  WAITVM(4); BAR(); OUT_COMPUTE(0);   // stage 30
  WAITVM(0); BAR(); OUT_COMPUTE(1);   // stage 31

#pragma unroll
  for (int i = 0; i < 4; ++i)
#pragma unroll
    for (int j = 0; j < 4; ++j) {
      const int col = bn * 128 + wn + j * 16 + l16;
      const float bv = bo[col];
#pragma unroll
      for (int r = 0; r < 4; ++r) {
        const int row = bm * 128 + wm + i * 16 + quad * 4 + r;
        out[(size_t)row * D_MODEL + col] = acc[i][j][r] + bv;
      }
    }
#undef OUT_ISSUE
#undef OUT_COMPUTE
}

// ---------------- flash attention (round-4 VERIFIED kernel, verbatim) -------------
// Two 32-row q-sets per wave (block = 128 q-rows, grid 512): every ds_read_b128
// K/V fragment feeds TWO MFMAs with independent accumulators.  Robust
// one-vmcnt(0)-per-tile pipeline; sequential softmax per q-set;
// __launch_bounds__(256,1).  Measured: 49.9 us, VGPR 128, conflicts 2.1M, PASS.
__global__ void __launch_bounds__(256, 1) attn(const unsigned short* __restrict__ Qh,
                                               const unsigned short* __restrict__ Kh,
                                               const unsigned short* __restrict__ Vt,
                                               unsigned short* __restrict__ AO) {
  __shared__ __align__(16) char smem[65536];
  // stage p: Ks = smem + p*32768          [128 key][64 dh], XOR-swizzled
  //          Vs = smem + p*32768 + 16384  [64 d][128 key],  XOR-swizzled

  const int bid = blockIdx.x;
  const int qt = bid >> 5, head = bid & 31, b = head >> 4, h = head & 15;
  const int tid = threadIdx.x;
  const int lane = tid & 63, wave = tid >> 6;
  const int wq = wave >> 1, wk = wave & 1;
  const int l31 = lane & 31, hh = lane >> 5;

  const unsigned short* Qhead = Qh + (size_t)(b * HEADS + h) * SEQ * DH;
  const unsigned short* Khead = Kh + (size_t)(b * HEADS + h) * SEQ * DH;
  const unsigned short* Vhead = Vt + (size_t)(b * HEADS + h) * DH * SEQ;

  const int qrow0 = qt * 128 + wq * 64 + l31;   // q-set 0; q-set 1 = +32
  bf16x8 aq0[4], aq1[4];
#pragma unroll
  for (int it = 0; it < 4; ++it) {
    aq0[it] = *(const bf16x8*)&Qhead[(size_t)qrow0 * DH + it * 16 + hh * 8];
    aq1[it] = *(const bf16x8*)&Qhead[(size_t)(qrow0 + 32) * DH + it * 16 + hh * 8];
  }

  f32x16 oacc0[2] = {}, oacc1[2] = {};
  float lsum0 = 0.f, lsum1 = 0.f;

#define ATT_STAGE(KC, P)                                                      \
  do {                                                                        \
    unsigned short* Ksp = (unsigned short*)(smem + (P) * 32768);              \
    unsigned short* Vsp = (unsigned short*)(smem + (P) * 32768 + 16384);      \
    _Pragma("unroll") for (int c = 0; c < 4; ++c) {                           \
      int s = c * 256 + tid;                                                  \
      int row = s >> 3, pblk = s & 7;                                         \
      int jb = pblk ^ (row & 7);                                              \
      cp16(Khead + (size_t)((KC) * 128 + row) * DH + jb * 8, &Ksp[s * 8]);    \
    }                                                                         \
    _Pragma("unroll") for (int c = 0; c < 4; ++c) {                           \
      int s = c * 256 + tid;                                                  \
      int d = s >> 4, pblk = s & 15;                                          \
      int jb = pblk ^ (d & 7);                                                \
      cp16(Vhead + (size_t)d * SEQ + (KC) * 128 + jb * 8, &Vsp[s * 8]);       \
    }                                                                         \
  } while (0)

#define ATT_SOFTMAX(SA, PB, LSUM)                                             \
  do {                                                                        \
    float p[16];                                                              \
    _Pragma("unroll") for (int r = 0; r < 16; ++r) {                          \
      p[r] = __builtin_amdgcn_exp2f((SA)[r]);                                 \
      (LSUM) += p[r];                                                         \
    }                                                                         \
    _Pragma("unroll") for (int c = 0; c < 2; ++c) {                           \
      unsigned x0 = pkbf(p[8 * c + 0], p[8 * c + 1]);                         \
      unsigned x1 = pkbf(p[8 * c + 2], p[8 * c + 3]);                         \
      unsigned y0 = pkbf(p[8 * c + 4], p[8 * c + 5]);                         \
      unsigned y1 = pkbf(p[8 * c + 6], p[8 * c + 7]);                         \
      asm("v_permlane32_swap_b32 %0, %1" : "+v"(x0), "+v"(y0));               \
      asm("v_permlane32_swap_b32 %0, %1" : "+v"(x1), "+v"(y1));               \
      union { unsigned u[4]; bf16x8 s; } pbu;                                 \
      pbu.u[0] = x0; pbu.u[1] = x1; pbu.u[2] = y0; pbu.u[3] = y1;             \
      (PB)[c] = pbu.s;                                                        \
    }                                                                         \
  } while (0)

#define ATT_COMPUTE(P)                                                        \
  do {                                                                        \
    const unsigned short* Ksp = (const unsigned short*)(smem + (P) * 32768);  \
    const unsigned short* Vsp =                                               \
        (const unsigned short*)(smem + (P) * 32768 + 16384);                  \
    __builtin_amdgcn_s_setprio(1);                                            \
    _Pragma("unroll") for (int sub = 0; sub < 2; ++sub) {                     \
      const int key = sub * 64 + wk * 32 + l31;                               \
      bf16x8 ak[4];                                                           \
      _Pragma("unroll") for (int it = 0; it < 4; ++it) {                      \
        const int sblk = (2 * it + hh) ^ (key & 7);                           \
        ak[it] = *(const bf16x8*)&Ksp[key * 64 + sblk * 8];                   \
      }                                                                       \
      bf16x8 pb0[2], pb1[2];                                                  \
      {                                                                       \
        f32x16 sa = {};                                                       \
        _Pragma("unroll") for (int it = 0; it < 4; ++it)                      \
          sa = __builtin_amdgcn_mfma_f32_32x32x16_bf16(ak[it], aq0[it], sa,   \
                                                       0, 0, 0);              \
        ATT_SOFTMAX(sa, pb0, lsum0);                                          \
      }                                                                       \
      {                                                                       \
        f32x16 sa = {};                                                       \
        _Pragma("unroll") for (int it = 0; it < 4; ++it)                      \
          sa = __builtin_amdgcn_mfma_f32_32x32x16_bf16(ak[it], aq1[it], sa,   \
                                                       0, 0, 0);              \
        ATT_SOFTMAX(sa, pb1, lsum1);                                          \
      }                                                                       \
      _Pragma("unroll") for (int c = 0; c < 2; ++c) {                         \
        const int K8 = sub * 8 + wk * 4 + 2 * c + hh;                         \
        _Pragma("unroll") for (int dh2 = 0; dh2 < 2; ++dh2) {                 \
          const int d = dh2 * 32 + l31;                                       \
          const int sv = K8 ^ (d & 7);                                        \
          bf16x8 av = *(const bf16x8*)&Vsp[d * 128 + sv * 8];                 \
          oacc0[dh2] = __builtin_amdgcn_mfma_f32_32x32x16_bf16(av, pb0[c],    \
                                                               oacc0[dh2],   \
                                                               0, 0, 0);     \
          oacc1[dh2] = __builtin_amdgcn_mfma_f32_32x32x16_bf16(av, pb1[c],    \
                                                               oacc1[dh2],   \
                                                               0, 0, 0);     \
        }                                                                     \
      }                                                                       \
    }                                                                         \
    __builtin_amdgcn_s_setprio(0);                                            \
  } while (0)

  ATT_STAGE(0, 0);
  for (int kc = 0; kc < 16; ++kc) {
    WAITVM(0);                          // tile kc's loads (and ANY stray vmem) done
    BAR();                              // all waves' stage-kc data visible
    if (kc < 15) ATT_STAGE(kc + 1, (kc + 1) & 1);  // next tile flies during compute
    ATT_COMPUTE(kc & 1);
    BAR();                              // all waves done reading buf kc&1
  }

  lsum0 += __shfl_xor(lsum0, 32);
  lsum1 += __shfl_xor(lsum1, 32);

  // epilogue scratch overlays stage 0 (last read at kc=14; final BAR passed)
  float* epiF = (float*)smem;                            // [2 wq][2048]
  float* lbuf = (float*)(smem + 16384);                  // [4][32]
  unsigned short* Oq = (unsigned short*)(smem + 17408);  // [2 wq][32 q][68]

#define ATT_EPI(OACC, LSUM, SET)                                              \
  do {                                                                        \
    if (lane < 32) lbuf[wave * 32 + l31] = (LSUM);                            \
    if (wk == 1) {                                                            \
      _Pragma("unroll") for (int dh2 = 0; dh2 < 2; ++dh2)                     \
        _Pragma("unroll") for (int r = 0; r < 16; ++r) {                      \
          const int d = dh2 * 32 + (r & 3) + 8 * (r >> 2) + 4 * hh;           \
          epiF[wq * 2048 + d * 32 + l31] = (OACC)[dh2][r];                    \
        }                                                                     \
    }                                                                         \
    __syncthreads();                                                          \
    if (wk == 0) {                                                            \
      const float linv = 1.0f / ((LSUM) + lbuf[(wq * 2 + 1) * 32 + l31]);     \
      _Pragma("unroll") for (int dh2 = 0; dh2 < 2; ++dh2) {                   \
        _Pragma("unroll") for (int r = 0; r < 16; r += 2) {                   \
          const int d = dh2 * 32 + (r & 3) + 8 * (r >> 2) + 4 * hh;           \
          const float v0 =                                                    \
              ((OACC)[dh2][r] + epiF[wq * 2048 + d * 32 + l31]) * linv;       \
          const float v1 =                                                    \
              ((OACC)[dh2][r + 1] + epiF[wq * 2048 + (d + 1) * 32 + l31]) *   \
              linv;                                                           \
          *(unsigned*)&Oq[wq * 2176 + l31 * 68 + d] = pkbf(v0, v1);           \
        }                                                                     \
      }                                                                       \
    }                                                                         \
    __syncthreads();                                                          \
    {                                                                         \
      const int qloc = tid >> 2, d0 = (tid & 3) * 16;                         \
      const int base = (qloc >> 5) * 2176 + (qloc & 31) * 68 + d0;            \
      unsigned u[8];                                                          \
      _Pragma("unroll") for (int i = 0; i < 8; ++i)                           \
        u[i] = *(const unsigned*)&Oq[base + i * 2];                           \
      const int row = qt * 128 + (qloc >> 5) * 64 + (SET) * 32 + (qloc & 31); \
      unsigned short* dst =                                                   \
          AO + ((size_t)(b * SEQ + row)) * D_MODEL + h * 64 + d0;             \
      *(uint4*)dst       = make_uint4(u[0], u[1], u[2], u[3]);                \
      *(uint4*)(dst + 8) = make_uint4(u[4], u[5], u[6], u[7]);                \
    }                                                                         \
  } while (0)

  ATT_EPI(oacc0, lsum0, 0);
  __syncthreads();
  ATT_EPI(oacc1, lsum1, 1);

#undef ATT_STAGE
#undef ATT_SOFTMAX
#undef ATT_COMPUTE
#undef ATT_EPI
}

extern "C" void kernel_launch(void* const* d_in, const int* in_sizes, int n_in,
                              void* d_out, int out_size, void* d_ws, size_t ws_size,
                              hipStream_t stream) {
  const float* q  = (const float*)d_in[0];
  const float* k  = (const float*)d_in[1];
  const float* v  = (const float*)d_in[2];
  const float* Wq = (const float*)d_in[3];
  const float* bq = (const float*)d_in[4];
  const float* Wk = (const float*)d_in[5];
  const float* bk = (const float*)d_in[6];
  const float* Wv = (const float*)d_in[7];
  const float* bv = (const float*)d_in[8];
  const float* Wo = (const float*)d_in[9];
  const float* bo = (const float*)d_in[10];
  float* out = (float*)d_out;

  char* ws = (char*)d_ws;
  const size_t MB = 1ull << 20;
  unsigned short* qb  = (unsigned short*)(ws + 0 * MB);
  unsigned short* kb  = (unsigned short*)(ws + 8 * MB);
  unsigned short* vb  = (unsigned short*)(ws + 16 * MB);
  unsigned short* Wqb = (unsigned short*)(ws + 24 * MB);
  unsigned short* Wkb = (unsigned short*)(ws + 26 * MB);
  unsigned short* Wvb = (unsigned short*)(ws + 28 * MB);
  unsigned short* Wob = (unsigned short*)(ws + 30 * MB);
  unsigned short* Qh  = (unsigned short*)(ws + 32 * MB);
  unsigned short* Kh  = (unsigned short*)(ws + 40 * MB);
  unsigned short* Vt  = (unsigned short*)(ws + 48 * MB);
  unsigned short* AO  = (unsigned short*)(ws + 56 * MB);

  castall<<<16384, 256, 0, stream>>>(q, k, v, Wq, Wk, Wv, Wo,
                                     qb, kb, vb, Wqb, Wkb, Wvb, Wob);

  const float qscale = 0.125f * 1.44269504088896f;  // fold 1/sqrt(Dh) and log2(e) into Q
  qkv_gemm<<<768, 256, 0, stream>>>(qb, kb, vb, Wqb, Wkb, Wvb, bq, bk, bv,
                                    Qh, Kh, Vt, qscale);

  attn<<<512, 256, 0, stream>>>(Qh, Kh, Vt, AO);

  out_gemm<<<256, 256, 0, stream>>>(AO, Wob, bo, out);
}